// Round 3
// baseline (2389.148 us; speedup 1.0000x reference)
//
#include <hip/hip_runtime.h>
#include <hip/hip_bf16.h>
#include <math.h>

// Problem constants
#define BB 64
#define LL 200
#define NQ 1024
#define DD 256
#define HH 512
#define QQ 1024
#define G3 1536   // 3*H
#define BL 12800  // B*L
#define GBLK 512  // persistent GRU grid: 2 blocks/CU (phase-decoupled batch groups)
#define NBG 16    // batch groups (4 batches each)
#define NUG 32    // unit groups (16 units each)

// ---------------- workspace layout (in floats) ----------------
#define OFF_ACC   ((size_t)0)                    // [0]=creg_raw [1]=mse [2]=maskcnt
#define OFF_HA    ((size_t)1056)                 // (unused; hU aliases OFF_AQ)
#define OFF_AQ    (OFF_HA + 65536)               // 1025*1536  (dead after xgt -> reused as hU+cells)
#define OFF_DQ    (OFF_AQ + 1574400)
#define OFF_BQA   (OFF_DQ + 1574400)             // 2*1536
#define OFF_CQA   (OFF_BQA + 3072)
#define OFF_WSUM  (OFF_CQA + 3072)               // 1536*256
#define OFF_FCWT  (OFF_WSUM + 393216)            // 512*1024
#define OFF_M2    (OFF_FCWT + 524288)            // 1024*512
#define OFF_MB    (OFF_M2 + 524288)              // 1024
#define OFF_XG    (OFF_MB + 1024)                // xgP [16][200][1536][4] (also temp M2 splitk parts)
#define OFF_GRUT  (OFF_XG + 19660800)            // [t][b][k]
#define OFF_QINT  (OFF_GRUT + 6553600)           // 12800 ints [B][L]
#define OFF_QAINT (OFF_QINT + 12800)
#define OFF_PIDF  (OFF_QAINT + 12800)
#define OFF_MVAL  (OFF_PIDF + 12800)
#define OFF_MC    (OFF_MVAL + 12800)
#define OFF_MI    (OFF_MC + 12800)
#define OFF_NMC   (OFF_MI + 12800)
#define OFF_AA    (OFF_NMC + 12800)
#define OFF_PREDS (OFF_AA + 12800)

typedef float f32x4 __attribute__((ext_vector_type(4)));

__device__ __forceinline__ float wave_sum64(float v) {
    #pragma unroll
    for (int o = 32; o > 0; o >>= 1) v += __shfl_down(v, o, 64);
    return v;
}

// LLC-coherent (bypass L1/L2) ops
__device__ __forceinline__ f32x4 llc_load4w(const float* p) {
    f32x4 v;
    asm volatile("global_load_dwordx4 %0, %1, off sc0 sc1\n\ts_waitcnt vmcnt(0)"
                 : "=&v"(v) : "v"(p));
    return v;
}
__device__ __forceinline__ void llc_store1(float* p, float v) {
    asm volatile("global_store_dword %0, %1, off sc0 sc1" :: "v"(p), "v"(v) : "memory");
}

// quad (4-lane) butterfly sum via DPP quad_perm (VALU pipe, not LDS)
__device__ __forceinline__ float quad_sum(float v) {
    float t1 = __int_as_float(__builtin_amdgcn_update_dpp(
        0, __float_as_int(v), 0xB1, 0xF, 0xF, true));   // quad_perm xor1
    v += t1;
    float t2 = __int_as_float(__builtin_amdgcn_update_dpp(
        0, __float_as_int(v), 0x4E, 0xF, 0xF, true));   // quad_perm xor2
    return v + t2;
}

// raw block barrier: drain LDS only (NOT vmcnt -> keeps gruT2 store in flight)
__device__ __forceinline__ void block_sync_lds() {
    __builtin_amdgcn_sched_barrier(0);
    asm volatile("s_waitcnt lgkmcnt(0)" ::: "memory");
    __builtin_amdgcn_s_barrier();
    __builtin_amdgcn_sched_barrier(0);
}

// -------- meta: q, qa, pid per (b,t); c_reg accumulation --------
__global__ __launch_bounds__(256) void prep_meta(
    const int* __restrict__ q_data, const int* __restrict__ qa_data,
    const int* __restrict__ pid_data, const float* __restrict__ diff_parm,
    int* __restrict__ qint, int* __restrict__ qaint, float* __restrict__ pidf,
    float* __restrict__ acc)
{
    int r = blockIdx.x * 256 + threadIdx.x;
    float pp = 0.f;
    if (r < BL) {
        int q = q_data[r];
        qint[r] = q;
        qaint[r] = (qa_data[r] - q) / NQ;
        float pid = diff_parm[pid_data[r]];
        pidf[r] = pid;
        pp = pid * pid;
    }
    pp = wave_sum64(pp);
    __shared__ float sm[4];
    int lane = threadIdx.x & 63, w = threadIdx.x >> 6;
    if (lane == 0) sm[w] = pp;
    __syncthreads();
    if (threadIdx.x == 0) atomicAdd(&acc[0], sm[0] + sm[1] + sm[2] + sm[3]);
}

// -------- wsum[g,d] = w_ih[g,d] + w_ih[g,256+d] --------
__global__ __launch_bounds__(256) void wsum_kernel(const float* __restrict__ w_ih,
                                                   float* __restrict__ wsum)
{
    int g = blockIdx.x, d = threadIdx.x;
    wsum[(size_t)g * DD + d] = w_ih[(size_t)g * 2 * DD + d] + w_ih[(size_t)g * 2 * DD + DD + d];
}

// -------- transpose [R,C] -> [C,R] --------
__global__ __launch_bounds__(256) void transpose_kernel(const float* __restrict__ in,
                                                        float* __restrict__ out, int R, int C)
{
    __shared__ float tile[32][33];
    int r0 = blockIdx.y * 32, c0 = blockIdx.x * 32;
    int tx = threadIdx.x & 31, ty = threadIdx.x >> 5;
    #pragma unroll
    for (int i = 0; i < 32; i += 8) {
        int r = r0 + ty + i, c = c0 + tx;
        if (r < R && c < C) tile[ty + i][tx] = in[(size_t)r * C + c];
    }
    __syncthreads();
    #pragma unroll
    for (int i = 0; i < 32; i += 8) {
        int c = c0 + ty + i, r = r0 + tx;
        if (c < C && r < R) out[(size_t)c * R + r] = tile[tx][ty + i];
    }
}

// -------- dual-batched NT GEMM (two independent problems, z picks) --------
__global__ __launch_bounds__(256) void gemm_nt_dual(
    const float* __restrict__ A0, const float* __restrict__ A1, int lda,
    const float* __restrict__ B0, const float* __restrict__ B1, int ldb0, int ldb1,
    float* __restrict__ C0, float* __restrict__ C1, int ldc,
    int M, int N, int K,
    const float* __restrict__ bias0, const float* __restrict__ bias1)
{
    const int z = blockIdx.z;
    const float* A = z ? A1 : A0;
    const float* B = z ? B1 : B0;
    float* C = z ? C1 : C0;
    const int ldb = z ? ldb1 : ldb0;
    const float* bias = z ? bias1 : bias0;

    __shared__ float As[16][65];
    __shared__ float Bs[16][65];
    const int bm = blockIdx.y * 64, bn = blockIdx.x * 64;
    const int tid = threadIdx.x;
    const int tx = tid & 15, ty = tid >> 4;
    const int mm = tid >> 4, kk = tid & 15;
    float acc[4][4] = {};
    float ar[4], br[4];
    #pragma unroll
    for (int i = 0; i < 4; ++i) {
        int m = bm + mm + 16 * i;
        ar[i] = (m < M) ? A[(size_t)m * lda + kk] : 0.f;
        int n = bn + mm + 16 * i;
        br[i] = (n < N) ? B[(size_t)n * ldb + kk] : 0.f;
    }
    for (int k0 = 0; k0 < K; k0 += 16) {
        #pragma unroll
        for (int i = 0; i < 4; ++i) { As[kk][mm + 16 * i] = ar[i]; Bs[kk][mm + 16 * i] = br[i]; }
        __syncthreads();
        int kn = k0 + 16;
        if (kn < K) {
            #pragma unroll
            for (int i = 0; i < 4; ++i) {
                int m = bm + mm + 16 * i;
                ar[i] = (m < M) ? A[(size_t)m * lda + kn + kk] : 0.f;
                int n = bn + mm + 16 * i;
                br[i] = (n < N) ? B[(size_t)n * ldb + kn + kk] : 0.f;
            }
        }
        #pragma unroll
        for (int kq = 0; kq < 16; ++kq) {
            float a[4], b[4];
            #pragma unroll
            for (int i = 0; i < 4; ++i) a[i] = As[kq][ty * 4 + i];
            #pragma unroll
            for (int j = 0; j < 4; ++j) b[j] = Bs[kq][tx * 4 + j];
            #pragma unroll
            for (int i = 0; i < 4; ++i)
                #pragma unroll
                for (int j = 0; j < 4; ++j) acc[i][j] += a[i] * b[j];
        }
        __syncthreads();
    }
    #pragma unroll
    for (int i = 0; i < 4; ++i) {
        int m = bm + ty * 4 + i;
        if (m >= M) continue;
        #pragma unroll
        for (int j = 0; j < 4; ++j) {
            int n = bn + tx * 4 + j;
            if (n >= N) continue;
            C[(size_t)m * ldc + n] = acc[i][j] + (bias ? bias[n] : 0.f);
        }
    }
}

// -------- split-K NT GEMM: Cp[z] = A[:, zK4:(z+1)K4] . B[:, same]^T --------
__global__ __launch_bounds__(256) void gemm_nt_splitk(
    const float* __restrict__ Ain, int lda,
    const float* __restrict__ Bin, int ldb,
    float* __restrict__ Cp, int ldc,
    int M, int N, int K4)
{
    const int z = blockIdx.z;
    const float* A = Ain + (size_t)z * K4;
    const float* B = Bin + (size_t)z * K4;
    float* C = Cp + (size_t)z * M * ldc;

    __shared__ float As[16][65];
    __shared__ float Bs[16][65];
    const int bm = blockIdx.y * 64, bn = blockIdx.x * 64;
    const int tid = threadIdx.x;
    const int tx = tid & 15, ty = tid >> 4;
    const int mm = tid >> 4, kk = tid & 15;
    float acc[4][4] = {};
    float ar[4], br[4];
    #pragma unroll
    for (int i = 0; i < 4; ++i) {
        int m = bm + mm + 16 * i;
        ar[i] = (m < M) ? A[(size_t)m * lda + kk] : 0.f;
        int n = bn + mm + 16 * i;
        br[i] = (n < N) ? B[(size_t)n * ldb + kk] : 0.f;
    }
    for (int k0 = 0; k0 < K4; k0 += 16) {
        #pragma unroll
        for (int i = 0; i < 4; ++i) { As[kk][mm + 16 * i] = ar[i]; Bs[kk][mm + 16 * i] = br[i]; }
        __syncthreads();
        int kn = k0 + 16;
        if (kn < K4) {
            #pragma unroll
            for (int i = 0; i < 4; ++i) {
                int m = bm + mm + 16 * i;
                ar[i] = (m < M) ? A[(size_t)m * lda + kn + kk] : 0.f;
                int n = bn + mm + 16 * i;
                br[i] = (n < N) ? B[(size_t)n * ldb + kn + kk] : 0.f;
            }
        }
        #pragma unroll
        for (int kq = 0; kq < 16; ++kq) {
            float a[4], b[4];
            #pragma unroll
            for (int i = 0; i < 4; ++i) a[i] = As[kq][ty * 4 + i];
            #pragma unroll
            for (int j = 0; j < 4; ++j) b[j] = Bs[kq][tx * 4 + j];
            #pragma unroll
            for (int i = 0; i < 4; ++i)
                #pragma unroll
                for (int j = 0; j < 4; ++j) acc[i][j] += a[i] * b[j];
        }
        __syncthreads();
    }
    #pragma unroll
    for (int i = 0; i < 4; ++i) {
        int m = bm + ty * 4 + i;
        if (m >= M) continue;
        #pragma unroll
        for (int j = 0; j < 4; ++j) {
            int n = bn + tx * 4 + j;
            if (n >= N) continue;
            C[(size_t)m * ldc + n] = acc[i][j];
        }
    }
}

__global__ __launch_bounds__(256) void reduce4_kernel(const float* __restrict__ p,
                                                      float* __restrict__ o, int n)
{
    int i = blockIdx.x * 256 + threadIdx.x;
    if (i < n) o[i] = p[i] + p[n + i] + p[2 * n + i] + p[3 * n + i];
}

// -------- mb[k] = sum_q matrix[k,q]*fc_b[q] --------
__global__ __launch_bounds__(256) void mb_kernel(const float* __restrict__ matrix,
                                                 const float* __restrict__ fc_b,
                                                 float* __restrict__ mb)
{
    int k = blockIdx.x;
    float s = 0.f;
    for (int q = threadIdx.x; q < QQ; q += 256) s += matrix[(size_t)k * QQ + q] * fc_b[q];
    s = wave_sum64(s);
    __shared__ float sm[4];
    int lane = threadIdx.x & 63, w = threadIdx.x >> 6;
    if (lane == 0) sm[w] = s;
    __syncthreads();
    if (threadIdx.x == 0) mb[k] = sm[0] + sm[1] + sm[2] + sm[3];
}

// -------- fused xg gather + transpose into xgP[bg][t][g][4] --------
__global__ __launch_bounds__(512) void xgt_kernel(
    const float* __restrict__ Aq, const float* __restrict__ Bqa,
    const float* __restrict__ Cqa, const float* __restrict__ Dq,
    const int* __restrict__ qint, const int* __restrict__ qaint,
    const float* __restrict__ pidf, float* __restrict__ xgP)
{
    const int t = blockIdx.x;
    __shared__ float tile[64][136];
    __shared__ int qs[BB];
    __shared__ int qas[BB];
    __shared__ float ps[BB];
    const int tid = threadIdx.x;
    if (tid < BB) {
        qs[tid] = qint[tid * LL + t];
        qas[tid] = qaint[tid * LL + t];
        ps[tid] = pidf[tid * LL + t];
    }
    __syncthreads();
    for (int g0 = 0; g0 < G3; g0 += 128) {
        #pragma unroll
        for (int it = 0; it < 16; ++it) {
            int idx = it * 512 + tid;
            int b = idx >> 7, gg = idx & 127;
            int g = g0 + gg;
            int q = qs[b], qa = qas[b];
            float pid = ps[b];
            tile[b][gg] = Aq[(size_t)q * G3 + g] + Bqa[(size_t)qa * G3 + g]
                        + pid * (Cqa[(size_t)qa * G3 + g] + Dq[(size_t)q * G3 + g]);
        }
        __syncthreads();
        // dense writes: per bq, 512 threads cover (gg 0..127, bl 0..3) = 2KB contiguous
        #pragma unroll
        for (int bq = 0; bq < 16; ++bq) {
            int gg = tid >> 2, bl = tid & 3;
            xgP[(((size_t)bq * LL + t) * G3 + g0 + gg) * 4 + bl] = tile[bq * 4 + bl][gg];
        }
        __syncthreads();
    }
}

// ================== persistent GRU v3: 16 bg x 32 ug, 2 blocks/CU ==================
// Block (bg,ug): 4 batches x 16 units. Weights in registers (48 floats/lane).
// Chain-shortening vs R1: (1) single-wave epilogue -> signal right after wave-0's
// own vmcnt drain, no block barrier on the signal path; (2) gruT2 HBM store moved
// AFTER the signal (out of the drain); (3) xg staged in LDS one step ahead by
// wave 1 (no HBM latency in the chain); (4) raw s_barrier (lgkm-only drain) keeps
// the gruT2 store in flight; (5) 2 co-resident blocks from independent bgs fill
// each other's sync bubbles.
// Safety (G16): poll at end of step t-1 certifies all bg blocks completed step
// t-1 (incl. their gen t-1 staging), so step t's epilogue overwrite of parity
// (t+1)&1 (gen t-1) never races a reader. h stores drain (per-wave vmcnt(0))
// before the arrival store; pollers + stagers use device-scope (LLC) accesses.
__global__ __launch_bounds__(512, 4) void gru_persist(
    const float* __restrict__ xgP,     // [16][200][1536][4]
    const float* __restrict__ w_hh,    // [1536][512]
    const float* __restrict__ b_hh,    // [1536]
    float* __restrict__ hU,            // [2][64][512]
    float* __restrict__ gruT2,         // [200][64][512]
    unsigned int* __restrict__ cells)  // [16][32] cells, 64B apart
{
    __shared__ __align__(16) float hs[8][256];        // per-wave h slice (4b x 64k, rot-swizzled) 8KB
    __shared__ __align__(16) float part[8][3][16][4]; // wave partials 6KB
    __shared__ float xgl[2][3][64];                   // xg double buffer 1.5KB

    const int tid = threadIdx.x;
    const int bid = blockIdx.x;
    const int bg = bid >> 5;              // batch group (4 batches), blocks of a bg contiguous
    const int ug = bid & 31;              // unit group (16 units)
    const int j0 = ug * 16;
    const int wv = tid >> 6;              // 0..7 k-slice (64 k each)
    const int lane = tid & 63;
    const int g = lane >> 2;              // unit offset 0..15
    const int s = lane & 3;               // k sub-slice 0..3

    // ---- w_hh fragment in registers: 3 gates x 4 q x f32x4 = 48 floats/lane
    f32x4 ws4[3][4];
    #pragma unroll
    for (int gate = 0; gate < 3; ++gate)
        #pragma unroll
        for (int q = 0; q < 4; ++q)
            ws4[gate][q] = *(const f32x4*)&w_hh[
                (size_t)(gate * HH + j0 + g) * HH + wv * 64 + q * 16 + s * 4];

    // epilogue mapping (wave 0 only): u = lane>>2 (0..15), b = lane&3 (0..3)
    const int eu = lane >> 2;
    const int eb = lane & 3;
    const int ej = j0 + eu;
    float bhr = 0.f, bhz = 0.f, bhn = 0.f;
    if (wv == 0) {
        bhr = b_hh[ej];
        bhz = b_hh[HH + ej];
        bhn = b_hh[2 * HH + ej];
    }

    // staging split: lane covers (bp = lane>>4, kc0 = lane&15) 16B chunk
    const int bp = lane >> 4;
    const int kc0 = lane & 15;

    // prologue: wave 1 fills xgl[0] with t=0 inputs
    if (wv == 1) {
        const float* xb = xgP + ((size_t)bg * LL + 0) * (G3 * 4) + (size_t)j0 * 4 + lane;
        float a0 = xb[0];
        float a1 = xb[HH * 4];
        float a2 = xb[2 * HH * 4];
        xgl[0][0][lane] = a0;
        xgl[0][1][lane] = a1;
        xgl[0][2][lane] = a2;
    }
    block_sync_lds();

    for (int t = 0; t < LL; ++t) {
        // ---- stage h[t&1] slice: one coherent dwordx4 per lane, rot-swizzled LDS
        {
            const float* hc = hU + (size_t)(t & 1) * (BB * HH)
                            + (size_t)(bg * 4 + bp) * HH + wv * 64 + kc0 * 4;
            f32x4 v = llc_load4w(hc);
            *(f32x4*)&hs[wv][kc0 * 16 + ((bp + (kc0 >> 1)) & 3) * 4] = v;
        }

        // ---- FMA: 16 ds_read_b128 (16-lane broadcast, conflict-free), 192 v_fma
        float a0[4] = {}, a1[4] = {}, a2[4] = {};
        #pragma unroll
        for (int q = 0; q < 4; ++q) {
            const int kc = q * 4 + s;
            const f32x4 w0 = ws4[0][q], w1 = ws4[1][q], w2 = ws4[2][q];
            #pragma unroll
            for (int bb = 0; bb < 4; ++bb) {
                f32x4 h4 = *(const f32x4*)&hs[wv][kc * 16 + ((bb + (kc >> 1)) & 3) * 4];
                a0[bb] += w0.x * h4.x + w0.y * h4.y + w0.z * h4.z + w0.w * h4.w;
                a1[bb] += w1.x * h4.x + w1.y * h4.y + w1.z * h4.z + w1.w * h4.w;
                a2[bb] += w2.x * h4.x + w2.y * h4.y + w2.z * h4.z + w2.w * h4.w;
            }
        }
        // k-reduce across the 4 s-lanes of each quad (VALU DPP)
        #pragma unroll
        for (int bb = 0; bb < 4; ++bb) {
            a0[bb] = quad_sum(a0[bb]);
            a1[bb] = quad_sum(a1[bb]);
            a2[bb] = quad_sum(a2[bb]);
        }
        // lane s (<3) writes gate-s partials (static indexing; exact-fit banks)
        if (s == 0)      *(f32x4*)&part[wv][0][g][0] = (f32x4){a0[0], a0[1], a0[2], a0[3]};
        else if (s == 1) *(f32x4*)&part[wv][1][g][0] = (f32x4){a1[0], a1[1], a1[2], a1[3]};
        else if (s == 2) *(f32x4*)&part[wv][2][g][0] = (f32x4){a2[0], a2[1], a2[2], a2[3]};
        block_sync_lds();   // sync1: partials ready, hs stable

        if (wv == 0) {
            // ---- epilogue (one wave = 16 units x 4 batches)
            float sg0 = 0.f, sg1 = 0.f, sg2 = 0.f;
            #pragma unroll
            for (int w = 0; w < 8; ++w) {
                sg0 += part[w][0][eu][eb];
                sg1 += part[w][1][eu][eb];
                sg2 += part[w][2][eu][eb];
            }
            const int slab = ug >> 2;
            const int kch = ((ug & 3) << 2) + (eu >> 2);
            float hprev = hs[slab][kch * 16 + ((eb + (kch >> 1)) & 3) * 4 + (eu & 3)];
            float xr = xgl[t & 1][0][lane];
            float xz = xgl[t & 1][1][lane];
            float xn = xgl[t & 1][2][lane];
            float rg = 1.f / (1.f + expf(-(xr + sg0 + bhr)));
            float zg = 1.f / (1.f + expf(-(xz + sg1 + bhz)));
            float ng = tanhf(xn + rg * (sg2 + bhn));
            float hn = (1.f - zg) * ng + zg * hprev;
            llc_store1(hU + (size_t)((t + 1) & 1) * (BB * HH)
                          + (size_t)(bg * 4 + eb) * HH + ej, hn);
            // drain THIS WAVE's h stores only, then signal (no block barrier)
            asm volatile("s_waitcnt vmcnt(0)" ::: "memory");
            if (lane == 0 && t + 1 < LL)
                __hip_atomic_store(&cells[(bg * 32 + ug) * 16], (unsigned)(t + 1),
                                   __ATOMIC_RELAXED, __HIP_MEMORY_SCOPE_AGENT);
            // HBM store AFTER the signal; stays in flight across the barrier
            gruT2[((size_t)t * BB + bg * 4 + eb) * HH + ej] = hn;
            // ---- poll gen t+1 from all 32 producers of this bg
            if (t + 1 < LL) {
                const unsigned want = (unsigned)(t + 1);
                for (;;) {
                    unsigned v = want;
                    if (lane < 32)
                        v = __hip_atomic_load(&cells[(bg * 32 + lane) * 16],
                                              __ATOMIC_RELAXED, __HIP_MEMORY_SCOPE_AGENT);
                    if (__all((int)(v >= want))) break;
                }
            }
        } else if (wv == 1) {
            // ---- xg prefetch for t+1 into the other xgl buffer
            if (t + 1 < LL) {
                const float* xb = xgP + ((size_t)bg * LL + (t + 1)) * (G3 * 4)
                                + (size_t)j0 * 4 + lane;
                float v0 = xb[0];
                float v1 = xb[HH * 4];
                float v2 = xb[2 * HH * 4];
                xgl[(t + 1) & 1][0][lane] = v0;
                xgl[(t + 1) & 1][1][lane] = v1;
                xgl[(t + 1) & 1][2][lane] = v2;
            }
        }
        block_sync_lds();   // sync2: h gen t+1 ready (wave0 polled), xgl ready, hs reusable
    }
}

// -------- mvals[b,t] = threshold( dot(h_t, M2[q-1]) + mb[q-1] ) --------
__global__ __launch_bounds__(256) void mval_kernel(
    const float* __restrict__ gruT2,   // [200][64][512]
    const float* __restrict__ M2,      // [1024][512]
    const float* __restrict__ mb,
    const int* __restrict__ qint,      // [B][L]
    float* __restrict__ mval)          // [B][L]
{
    int t = blockIdx.x;
    int wave = threadIdx.x >> 6, l = threadIdx.x & 63;
    for (int ii = 0; ii < 16; ++ii) {
        int b = wave * 16 + ii;
        int q = qint[b * LL + t] - 1;
        const float4* hp = (const float4*)(gruT2 + ((size_t)t * BB + b) * HH);
        const float4* mp = (const float4*)(M2 + (size_t)q * HH);
        float4 h0 = hp[l], m0 = mp[l];
        float4 h1 = hp[64 + l], m1 = mp[64 + l];
        float acc = h0.x * m0.x + h0.y * m0.y + h0.z * m0.z + h0.w * m0.w
                  + h1.x * m1.x + h1.y * m1.y + h1.z * m1.z + h1.w * m1.w;
        acc = wave_sum64(acc);
        if (l == 0) {
            float sv = acc + mb[q];
            mval[b * LL + t] = (sv >= 0.4f) ? 1.0f : sv;
        }
    }
}

// -------- per-(b,t) counting statistics --------
__global__ __launch_bounds__(256) void stats_kernel(
    const int* __restrict__ qint, const int* __restrict__ qaint,
    const float* __restrict__ mval,
    float* __restrict__ mc, float* __restrict__ mi,
    float* __restrict__ nmc, float* __restrict__ aa)
{
    int b = blockIdx.x, tid = threadIdx.x;
    __shared__ int qs[LL];
    __shared__ int qas[LL];
    __shared__ float mv[LL];
    if (tid < LL) {
        qs[tid] = qint[b * LL + tid];
        qas[tid] = qaint[b * LL + tid];
        mv[tid] = mval[b * LL + tid];
    }
    __syncthreads();
    int t = tid;
    if (t < LL) {
        int qt = qs[t];
        float smc = 0.f, smi = 0.f, snmc = 0.f, saa = 0.f;
        for (int k = 0; k <= t; ++k) {
            if (qs[k] == qt) {
                saa += 1.f;
                if (k < t) {
                    float mk = (mv[k] == 1.f) ? 1.f : 0.f;
                    float nk = (mv[k] == 0.f) ? 1.f : 0.f;
                    float a1 = (qas[k] == 1) ? 1.f : 0.f;
                    smc += a1 * mk;
                    smi += (1.f - a1) * mk;
                    snmc += (1.f - a1) * nk;
                }
            }
        }
        mc[b * LL + t] = smc;
        mi[b * LL + t] = smi;
        nmc[b * LL + t] = snmc;
        aa[b * LL + t] = saa;
    }
}

// -------- sequential DINA scan per batch --------
__global__ __launch_bounds__(256) void dina_kernel(
    const int* __restrict__ qint, const int* __restrict__ qaint,
    const float* __restrict__ mval,
    const float* __restrict__ mc, const float* __restrict__ mi,
    const float* __restrict__ nmc, const float* __restrict__ aa,
    float* __restrict__ preds)
{
    int b = blockIdx.x, tid = threadIdx.x;
    __shared__ float guess[QQ], slip[QQ];
    __shared__ float s_m[LL], s_mc[LL], s_mi[LL], s_nmc[LL], s_aa[LL];
    __shared__ int s_i[LL], s_qa[LL];
    for (int i = tid; i < QQ; i += 256) { guess[i] = 0.f; slip[i] = 0.f; }
    if (tid < LL) {
        s_m[tid] = mval[b * LL + tid];
        s_mc[tid] = mc[b * LL + tid];
        s_mi[tid] = mi[b * LL + tid];
        s_nmc[tid] = nmc[b * LL + tid];
        s_aa[tid] = aa[b * LL + tid];
        s_i[tid] = qint[b * LL + tid] - 1;
        s_qa[tid] = qaint[b * LL + tid];
    }
    __syncthreads();
    if (tid == 0) {
        for (int t = 0; t < LL; ++t) {
            int i = s_i[t];
            float m = s_m[t];
            int qa = s_qa[t];
            float aat = s_aa[t];
            float g_upd = (m == 1.f) ? s_mc[t] / aat
                          : ((qa == 0) ? 1.f - s_nmc[t] / aat : s_nmc[t] / aat);
            bool us = (m == 1.f) && (qa == 0);
            float ng = us ? guess[i] : g_upd;
            float ns = us ? s_mi[t] / aat : slip[i];
            guess[i] = ng;
            slip[i] = ns;
            preds[b * LL + t] = (1.f - ns) * (m * ng + (1.f - ns) * (1.f - m));
        }
    }
}

// -------- masked MSE + sigmoid outputs --------
__global__ __launch_bounds__(256) void loss_kernel(
    const float* __restrict__ preds, const float* __restrict__ target,
    float* __restrict__ out, float* __restrict__ acc)
{
    int r = blockIdx.x * 256 + threadIdx.x;
    float lm = 0.f, lc = 0.f;
    if (r < BL) {
        float p = preds[r], lab = target[r];
        float msk = (lab > -0.9f) ? 1.f : 0.f;
        float d = p - lab;
        lm = d * d * msk;
        lc = msk;
        out[1 + r] = 1.f / (1.f + expf(-p));
    }
    lm = wave_sum64(lm);
    lc = wave_sum64(lc);
    __shared__ float sm[4], sc[4];
    int lane = threadIdx.x & 63, w = threadIdx.x >> 6;
    if (lane == 0) { sm[w] = lm; sc[w] = lc; }
    __syncthreads();
    if (threadIdx.x == 0) {
        atomicAdd(&acc[1], sm[0] + sm[1] + sm[2] + sm[3]);
        atomicAdd(&acc[2], sc[0] + sc[1] + sc[2] + sc[3]);
    }
}

__global__ void final_kernel(const float* __restrict__ acc, float* __restrict__ out)
{
    out[0] = acc[1] + acc[0] * 1e-5f;
    out[1 + BL] = acc[2];
}

extern "C" void kernel_launch(void* const* d_in, const int* in_sizes, int n_in,
                              void* d_out, int out_size, void* d_ws, size_t ws_size,
                              hipStream_t stream) {
    const int* q_data = (const int*)d_in[0];
    const int* qa_data = (const int*)d_in[1];
    const int* pid_data = (const int*)d_in[2];
    const float* matrix = (const float*)d_in[3];
    const float* target = (const float*)d_in[4];
    const float* q_emb = (const float*)d_in[5];
    const float* qa_emb = (const float*)d_in[6];
    const float* q_emb_diff = (const float*)d_in[7];
    const float* qa_emb_diff = (const float*)d_in[8];
    const float* diff_parm = (const float*)d_in[9];
    const float* w_ih = (const float*)d_in[10];
    const float* w_hh = (const float*)d_in[11];
    const float* b_ih = (const float*)d_in[12];
    const float* b_hh = (const float*)d_in[13];
    const float* fc_w = (const float*)d_in[14];
    const float* fc_b = (const float*)d_in[15];
    float* out = (float*)d_out;
    float* W = (float*)d_ws;

    float* acc = W + OFF_ACC;
    float* Aq = W + OFF_AQ;
    float* Dq = W + OFF_DQ;
    float* Bqa = W + OFF_BQA;
    float* Cqa = W + OFF_CQA;
    float* wsum = W + OFF_WSUM;
    float* fcwT = W + OFF_FCWT;
    float* M2 = W + OFF_M2;
    float* mb = W + OFF_MB;
    float* xgP = W + OFF_XG;
    float* m2parts = W + OFF_XG;       // temp: reused before xgP is written
    float* gruT2 = W + OFF_GRUT;
    int* qint = (int*)(W + OFF_QINT);
    int* qaint = (int*)(W + OFF_QAINT);
    float* pidf = W + OFF_PIDF;
    float* mval = W + OFF_MVAL;
    float* mc = W + OFF_MC;
    float* mi = W + OFF_MI;
    float* nmc = W + OFF_NMC;
    float* aa = W + OFF_AA;
    float* preds = W + OFF_PREDS;

    // hU (2*64*512) + cells (16*32*16 uints) alias the Aq region (dead after xgt)
    float* hU = W + OFF_AQ;
    unsigned int* cells = (unsigned int*)(hU + 2 * BB * HH);

    // zero accumulators
    hipMemsetAsync(W, 0, 1056 * sizeof(float), stream);

    prep_meta<<<50, 256, 0, stream>>>(q_data, qa_data, pid_data, diff_parm,
                                      qint, qaint, pidf, acc);
    wsum_kernel<<<G3, 256, 0, stream>>>(w_ih, wsum);
    transpose_kernel<<<dim3(16, 32), 256, 0, stream>>>(fc_w, fcwT, QQ, HH);

    // Bqa/Cqa batched
    gemm_nt_dual<<<dim3(24, 1, 2), 256, 0, stream>>>(
        qa_emb, qa_emb_diff, DD, w_ih, w_ih, 2 * DD, 2 * DD,
        Bqa, Cqa, G3, 2, G3, DD, b_ih, nullptr);
    // Aq/Dq batched
    gemm_nt_dual<<<dim3(24, 17, 2), 256, 0, stream>>>(
        q_emb, q_emb_diff, DD, wsum, w_ih + DD, DD, 2 * DD,
        Aq, Dq, G3, NQ + 1, G3, DD, nullptr, nullptr);
    // M2 = matrix . fc_w  (split-K x4 into temp region, then reduce)
    gemm_nt_splitk<<<dim3(8, 16, 4), 256, 0, stream>>>(
        matrix, QQ, fcwT, QQ, m2parts, HH, QQ, HH, QQ / 4);
    reduce4_kernel<<<2048, 256, 0, stream>>>(m2parts, M2, QQ * HH);
    mb_kernel<<<QQ, 256, 0, stream>>>(matrix, fc_b, mb);

    // xg gather+transpose into xgP (overwrites the m2parts temp region)
    xgt_kernel<<<LL, 512, 0, stream>>>(Aq, Bqa, Cqa, Dq, qint, qaint, pidf, xgP);

    // zero h double-buffer + cells (Aq now dead; stream-ordered after xgt)
    hipMemsetAsync(hU, 0, (2 * BB * HH + NBG * NUG * 16) * sizeof(float), stream);

    gru_persist<<<GBLK, 512, 0, stream>>>(xgP, w_hh, b_hh, hU, gruT2, cells);

    mval_kernel<<<LL, 256, 0, stream>>>(gruT2, M2, mb, qint, mval);
    stats_kernel<<<BB, 256, 0, stream>>>(qint, qaint, mval, mc, mi, nmc, aa);
    dina_kernel<<<BB, 256, 0, stream>>>(qint, qaint, mval, mc, mi, nmc, aa, preds);
    loss_kernel<<<50, 256, 0, stream>>>(preds, target, out, acc);
    final_kernel<<<1, 1, 0, stream>>>(acc, out);
}

// Round 4
// 1397.029 us; speedup vs baseline: 1.7102x; 1.7102x over previous
//
#include <hip/hip_runtime.h>
#include <hip/hip_bf16.h>
#include <math.h>

// Problem constants
#define BB 64
#define LL 200
#define NQ 1024
#define DD 256
#define HH 512
#define QQ 1024
#define G3 1536   // 3*H
#define BL 12800  // B*L
#define GBLK 256  // persistent GRU grid: 1 block/CU

// ---------------- workspace layout (in floats) ----------------
#define OFF_ACC   ((size_t)0)                    // [0]=creg_raw [1]=mse [2]=maskcnt
#define OFF_CELLS ((size_t)16)                   // 256 cells, 16B apart (1024 uints)
#define OFF_HA    ((size_t)1056)                 // hA[2][64][512] batch-major
#define OFF_AQ    (OFF_HA + 65536)               // 1025*1536
#define OFF_DQ    (OFF_AQ + 1574400)
#define OFF_BQA   (OFF_DQ + 1574400)             // 2*1536
#define OFF_CQA   (OFF_BQA + 3072)
#define OFF_WSUM  (OFF_CQA + 3072)               // 1536*256
#define OFF_FCWT  (OFF_WSUM + 393216)            // 512*1024
#define OFF_M2    (OFF_FCWT + 524288)            // 1024*512
#define OFF_MB    (OFF_M2 + 524288)              // 1024
#define OFF_XG    (OFF_MB + 1024)                // xgT [t][g][b] (also temp M2 splitk parts)
#define OFF_GRUT  (OFF_XG + 19660800)            // [t][b][k]
#define OFF_QINT  (OFF_GRUT + 6553600)           // 12800 ints [B][L]
#define OFF_QAINT (OFF_QINT + 12800)
#define OFF_PIDF  (OFF_QAINT + 12800)
#define OFF_MVAL  (OFF_PIDF + 12800)
#define OFF_MC    (OFF_MVAL + 12800)
#define OFF_MI    (OFF_MC + 12800)
#define OFF_NMC   (OFF_MI + 12800)
#define OFF_AA    (OFF_NMC + 12800)
#define OFF_PREDS (OFF_AA + 12800)

typedef float f32x4 __attribute__((ext_vector_type(4)));

__device__ __forceinline__ float wave_sum64(float v) {
    #pragma unroll
    for (int o = 32; o > 0; o >>= 1) v += __shfl_down(v, o, 64);
    return v;
}

// LLC-coherent (bypass L1/L2) ops
__device__ __forceinline__ f32x4 llc_load4(const float* p) {
    f32x4 v;
    asm volatile("global_load_dwordx4 %0, %1, off sc0 sc1" : "=v"(v) : "v"(p));
    return v;
}
__device__ __forceinline__ void llc_wait2(f32x4& a, f32x4& b) {
    asm volatile("s_waitcnt vmcnt(0)" : "+v"(a), "+v"(b));
}
__device__ __forceinline__ void llc_store1(float* p, float v) {
    asm volatile("global_store_dword %0, %1, off sc0 sc1" :: "v"(p), "v"(v) : "memory");
}

// quad (4-lane) butterfly sum via DPP quad_perm (VALU pipe, not LDS)
__device__ __forceinline__ float quad_sum(float v) {
    float t1 = __int_as_float(__builtin_amdgcn_update_dpp(
        0, __float_as_int(v), 0xB1, 0xF, 0xF, true));   // quad_perm xor1
    v += t1;
    float t2 = __int_as_float(__builtin_amdgcn_update_dpp(
        0, __float_as_int(v), 0x4E, 0xF, 0xF, true));   // quad_perm xor2
    return v + t2;
}

// raw block barrier: drain LDS only (NOT vmcnt -> keeps gruT2 store in flight)
__device__ __forceinline__ void block_sync_lds() {
    __builtin_amdgcn_sched_barrier(0);
    asm volatile("s_waitcnt lgkmcnt(0)" ::: "memory");
    __builtin_amdgcn_s_barrier();
    __builtin_amdgcn_sched_barrier(0);
}

// -------- meta: q, qa, pid per (b,t); c_reg accumulation --------
__global__ __launch_bounds__(256) void prep_meta(
    const int* __restrict__ q_data, const int* __restrict__ qa_data,
    const int* __restrict__ pid_data, const float* __restrict__ diff_parm,
    int* __restrict__ qint, int* __restrict__ qaint, float* __restrict__ pidf,
    float* __restrict__ acc)
{
    int r = blockIdx.x * 256 + threadIdx.x;
    float pp = 0.f;
    if (r < BL) {
        int q = q_data[r];
        qint[r] = q;
        qaint[r] = (qa_data[r] - q) / NQ;
        float pid = diff_parm[pid_data[r]];
        pidf[r] = pid;
        pp = pid * pid;
    }
    pp = wave_sum64(pp);
    __shared__ float sm[4];
    int lane = threadIdx.x & 63, w = threadIdx.x >> 6;
    if (lane == 0) sm[w] = pp;
    __syncthreads();
    if (threadIdx.x == 0) atomicAdd(&acc[0], sm[0] + sm[1] + sm[2] + sm[3]);
}

// -------- wsum[g,d] = w_ih[g,d] + w_ih[g,256+d] --------
__global__ __launch_bounds__(256) void wsum_kernel(const float* __restrict__ w_ih,
                                                   float* __restrict__ wsum)
{
    int g = blockIdx.x, d = threadIdx.x;
    wsum[(size_t)g * DD + d] = w_ih[(size_t)g * 2 * DD + d] + w_ih[(size_t)g * 2 * DD + DD + d];
}

// -------- transpose [R,C] -> [C,R] --------
__global__ __launch_bounds__(256) void transpose_kernel(const float* __restrict__ in,
                                                        float* __restrict__ out, int R, int C)
{
    __shared__ float tile[32][33];
    int r0 = blockIdx.y * 32, c0 = blockIdx.x * 32;
    int tx = threadIdx.x & 31, ty = threadIdx.x >> 5;
    #pragma unroll
    for (int i = 0; i < 32; i += 8) {
        int r = r0 + ty + i, c = c0 + tx;
        if (r < R && c < C) tile[ty + i][tx] = in[(size_t)r * C + c];
    }
    __syncthreads();
    #pragma unroll
    for (int i = 0; i < 32; i += 8) {
        int c = c0 + ty + i, r = r0 + tx;
        if (c < C && r < R) out[(size_t)c * R + r] = tile[tx][ty + i];
    }
}

// -------- dual-batched NT GEMM (two independent problems, z picks) --------
__global__ __launch_bounds__(256) void gemm_nt_dual(
    const float* __restrict__ A0, const float* __restrict__ A1, int lda,
    const float* __restrict__ B0, const float* __restrict__ B1, int ldb0, int ldb1,
    float* __restrict__ C0, float* __restrict__ C1, int ldc,
    int M, int N, int K,
    const float* __restrict__ bias0, const float* __restrict__ bias1)
{
    const int z = blockIdx.z;
    const float* A = z ? A1 : A0;
    const float* B = z ? B1 : B0;
    float* C = z ? C1 : C0;
    const int ldb = z ? ldb1 : ldb0;
    const float* bias = z ? bias1 : bias0;

    __shared__ float As[16][65];
    __shared__ float Bs[16][65];
    const int bm = blockIdx.y * 64, bn = blockIdx.x * 64;
    const int tid = threadIdx.x;
    const int tx = tid & 15, ty = tid >> 4;
    const int mm = tid >> 4, kk = tid & 15;
    float acc[4][4] = {};
    float ar[4], br[4];
    #pragma unroll
    for (int i = 0; i < 4; ++i) {
        int m = bm + mm + 16 * i;
        ar[i] = (m < M) ? A[(size_t)m * lda + kk] : 0.f;
        int n = bn + mm + 16 * i;
        br[i] = (n < N) ? B[(size_t)n * ldb + kk] : 0.f;
    }
    for (int k0 = 0; k0 < K; k0 += 16) {
        #pragma unroll
        for (int i = 0; i < 4; ++i) { As[kk][mm + 16 * i] = ar[i]; Bs[kk][mm + 16 * i] = br[i]; }
        __syncthreads();
        int kn = k0 + 16;
        if (kn < K) {
            #pragma unroll
            for (int i = 0; i < 4; ++i) {
                int m = bm + mm + 16 * i;
                ar[i] = (m < M) ? A[(size_t)m * lda + kn + kk] : 0.f;
                int n = bn + mm + 16 * i;
                br[i] = (n < N) ? B[(size_t)n * ldb + kn + kk] : 0.f;
            }
        }
        #pragma unroll
        for (int kq = 0; kq < 16; ++kq) {
            float a[4], b[4];
            #pragma unroll
            for (int i = 0; i < 4; ++i) a[i] = As[kq][ty * 4 + i];
            #pragma unroll
            for (int j = 0; j < 4; ++j) b[j] = Bs[kq][tx * 4 + j];
            #pragma unroll
            for (int i = 0; i < 4; ++i)
                #pragma unroll
                for (int j = 0; j < 4; ++j) acc[i][j] += a[i] * b[j];
        }
        __syncthreads();
    }
    #pragma unroll
    for (int i = 0; i < 4; ++i) {
        int m = bm + ty * 4 + i;
        if (m >= M) continue;
        #pragma unroll
        for (int j = 0; j < 4; ++j) {
            int n = bn + tx * 4 + j;
            if (n >= N) continue;
            C[(size_t)m * ldc + n] = acc[i][j] + (bias ? bias[n] : 0.f);
        }
    }
}

// -------- split-K NT GEMM: Cp[z] = A[:, zK4:(z+1)K4] . B[:, same]^T --------
__global__ __launch_bounds__(256) void gemm_nt_splitk(
    const float* __restrict__ Ain, int lda,
    const float* __restrict__ Bin, int ldb,
    float* __restrict__ Cp, int ldc,
    int M, int N, int K4)
{
    const int z = blockIdx.z;
    const float* A = Ain + (size_t)z * K4;
    const float* B = Bin + (size_t)z * K4;
    float* C = Cp + (size_t)z * M * ldc;

    __shared__ float As[16][65];
    __shared__ float Bs[16][65];
    const int bm = blockIdx.y * 64, bn = blockIdx.x * 64;
    const int tid = threadIdx.x;
    const int tx = tid & 15, ty = tid >> 4;
    const int mm = tid >> 4, kk = tid & 15;
    float acc[4][4] = {};
    float ar[4], br[4];
    #pragma unroll
    for (int i = 0; i < 4; ++i) {
        int m = bm + mm + 16 * i;
        ar[i] = (m < M) ? A[(size_t)m * lda + kk] : 0.f;
        int n = bn + mm + 16 * i;
        br[i] = (n < N) ? B[(size_t)n * ldb + kk] : 0.f;
    }
    for (int k0 = 0; k0 < K4; k0 += 16) {
        #pragma unroll
        for (int i = 0; i < 4; ++i) { As[kk][mm + 16 * i] = ar[i]; Bs[kk][mm + 16 * i] = br[i]; }
        __syncthreads();
        int kn = k0 + 16;
        if (kn < K4) {
            #pragma unroll
            for (int i = 0; i < 4; ++i) {
                int m = bm + mm + 16 * i;
                ar[i] = (m < M) ? A[(size_t)m * lda + kn + kk] : 0.f;
                int n = bn + mm + 16 * i;
                br[i] = (n < N) ? B[(size_t)n * ldb + kn + kk] : 0.f;
            }
        }
        #pragma unroll
        for (int kq = 0; kq < 16; ++kq) {
            float a[4], b[4];
            #pragma unroll
            for (int i = 0; i < 4; ++i) a[i] = As[kq][ty * 4 + i];
            #pragma unroll
            for (int j = 0; j < 4; ++j) b[j] = Bs[kq][tx * 4 + j];
            #pragma unroll
            for (int i = 0; i < 4; ++i)
                #pragma unroll
                for (int j = 0; j < 4; ++j) acc[i][j] += a[i] * b[j];
        }
        __syncthreads();
    }
    #pragma unroll
    for (int i = 0; i < 4; ++i) {
        int m = bm + ty * 4 + i;
        if (m >= M) continue;
        #pragma unroll
        for (int j = 0; j < 4; ++j) {
            int n = bn + tx * 4 + j;
            if (n >= N) continue;
            C[(size_t)m * ldc + n] = acc[i][j];
        }
    }
}

__global__ __launch_bounds__(256) void reduce4_kernel(const float* __restrict__ p,
                                                      float* __restrict__ o, int n)
{
    int i = blockIdx.x * 256 + threadIdx.x;
    if (i < n) o[i] = p[i] + p[n + i] + p[2 * n + i] + p[3 * n + i];
}

// -------- mb[k] = sum_q matrix[k,q]*fc_b[q] --------
__global__ __launch_bounds__(256) void mb_kernel(const float* __restrict__ matrix,
                                                 const float* __restrict__ fc_b,
                                                 float* __restrict__ mb)
{
    int k = blockIdx.x;
    float s = 0.f;
    for (int q = threadIdx.x; q < QQ; q += 256) s += matrix[(size_t)k * QQ + q] * fc_b[q];
    s = wave_sum64(s);
    __shared__ float sm[4];
    int lane = threadIdx.x & 63, w = threadIdx.x >> 6;
    if (lane == 0) sm[w] = s;
    __syncthreads();
    if (threadIdx.x == 0) mb[k] = sm[0] + sm[1] + sm[2] + sm[3];
}

// -------- fused xg gather + transpose: xgT[t][g][b] --------
__global__ __launch_bounds__(512) void xgt_kernel(
    const float* __restrict__ Aq, const float* __restrict__ Bqa,
    const float* __restrict__ Cqa, const float* __restrict__ Dq,
    const int* __restrict__ qint, const int* __restrict__ qaint,
    const float* __restrict__ pidf, float* __restrict__ xgT)
{
    const int t = blockIdx.x;
    __shared__ float tile[64][129];
    __shared__ int qs[BB];
    __shared__ int qas[BB];
    __shared__ float ps[BB];
    const int tid = threadIdx.x;
    if (tid < BB) {
        qs[tid] = qint[tid * LL + t];
        qas[tid] = qaint[tid * LL + t];
        ps[tid] = pidf[tid * LL + t];
    }
    __syncthreads();
    for (int g0 = 0; g0 < G3; g0 += 128) {
        #pragma unroll
        for (int it = 0; it < 16; ++it) {
            int idx = it * 512 + tid;
            int b = idx >> 7, gg = idx & 127;
            int g = g0 + gg;
            int q = qs[b], qa = qas[b];
            float pid = ps[b];
            tile[b][gg] = Aq[(size_t)q * G3 + g] + Bqa[(size_t)qa * G3 + g]
                        + pid * (Cqa[(size_t)qa * G3 + g] + Dq[(size_t)q * G3 + g]);
        }
        __syncthreads();
        #pragma unroll
        for (int it = 0; it < 16; ++it) {
            int idx = it * 512 + tid;
            int gg = idx >> 6, b = idx & 63;
            xgT[((size_t)t * G3 + g0 + gg) * BB + b] = tile[b][gg];
        }
        __syncthreads();
    }
}

// ================== persistent GRU v4: R1-852 structure, shortened chain ==================
// 256 blocks = 8 batch-groups x 32 unit-groups. Block (bg,ug): 8 batches x 16 units.
// Weights in registers (48 floats/lane). h exchange: hA[2][64][512] double-buffered
// via LLC, per-wave staged slice into hs (8KB/block/step -> 2MB/step chip-wide).
// Changes vs the verified 852us version (chain-local only):
//  (1) wave-0-only epilogue (2 outputs/lane): signal gated by wave-0's OWN vmcnt
//      drain; no block barrier on the epilogue->signal path (3 barriers -> 2).
//  (2) gruT2 HBM store issued AFTER the signal (HBM ack off the serial chain;
//      drains under the poll / next barrier).
//  (3) poll unchanged: wave 0, 32 cells, __all, s_sleep(2) backoff (R3's no-sleep
//      poll flooded the LLC: FETCH 147MB -> 4.4GB. Backoff is load-bearing.)
// Safety (G16): producers drain h stores (vmcnt 0) before the arrival store; a
// block's poll success at step t certifies all 32 bg-blocks produced gen t+1,
// which implies (their sync1) they staged gen t -> parity overwrite at t+2 never
// races a reader. Pollers/stagers use agent-scope (LLC) accesses throughout.
__global__ __launch_bounds__(512) void gru_persist(
    const float* __restrict__ xgT,     // [200][1536][64]
    const float* __restrict__ w_hh,    // [1536][512]
    const float* __restrict__ b_hh,    // [1536]
    float* __restrict__ hA,            // [2][64][512]  (batch-major)
    float* __restrict__ gruT2,         // [200][64][512]
    unsigned int* __restrict__ cells)  // 256 cells, 16B apart
{
    __shared__ __align__(16) float hs[8][512];        // per-wave h slice [8b][64k], rot-swizzled (16KB)
    __shared__ __align__(16) float part[8][3][16][8]; // wave partials (12KB)

    const int tid = threadIdx.x;
    const int bid = blockIdx.x;
    const int bg = bid >> 5;              // batch group 0..7 (8 batches)
    const int ug = bid & 31;              // unit group (16 units)
    const int j0 = ug * 16;
    const int wv = tid >> 6;              // 0..7 k-slice (64 k each)
    const int lane = tid & 63;
    const int g = lane >> 2;              // unit offset 0..15
    const int s = lane & 3;               // k sub-slice 0..3

    // ---- w_hh fragment in registers: 3 gates x 4 q x f32x4 = 48 floats/lane
    f32x4 ws4[3][4];
    #pragma unroll
    for (int gate = 0; gate < 3; ++gate)
        #pragma unroll
        for (int q = 0; q < 4; ++q)
            ws4[gate][q] = *(const f32x4*)&w_hh[
                (size_t)(gate * HH + j0 + g) * HH + wv * 64 + q * 16 + s * 4];

    // epilogue mapping (wave 0 only): unit eu = lane>>2 (0..15), batches e0 and e0+4
    const int eu = lane >> 2;
    const int e0 = lane & 3;
    const int rb = eu >> 2;
    const int ej = j0 + eu;
    const int slab = ej >> 6;             // == ug>>2
    const int kc = ej & 63;
    float bhr = 0.f, bhz = 0.f, bhn = 0.f;
    if (wv == 0) {
        bhr = b_hh[ej];
        bhz = b_hh[HH + ej];
        bhn = b_hh[2 * HH + ej];
    }

    // staging split: lane covers batches (b0, b0+4), k-chunk c0..c0+3
    const int b0 = lane >> 4;
    const int c0 = (lane & 15) * 4;

    for (int t = 0; t < LL; ++t) {
        // ---- stage h[t&1] slice: two coherent dwordx4 in flight, one wait
        {
            const float* hcur = hA + (size_t)(t & 1) * (HH * BB);
            const float* p0 = hcur + (size_t)(bg * 8 + b0) * HH + wv * 64 + c0;
            f32x4 va = llc_load4(p0);
            f32x4 vb = llc_load4(p0 + 4 * HH);
            llc_wait2(va, vb);
            *(f32x4*)&hs[wv][b0 * 64 + ((c0 + 8 * b0) & 63)] = va;
            *(f32x4*)&hs[wv][(b0 + 4) * 64 + ((c0 + 8 * b0 + 32) & 63)] = vb;
        }
        // wave 0: issue xg loads for this step (cached; consumed in epilogue)
        float xr0 = 0.f, xz0 = 0.f, xn0 = 0.f, xr1 = 0.f, xz1 = 0.f, xn1 = 0.f;
        if (wv == 0) {
            const float* xb = xgT + (size_t)t * (G3 * BB) + bg * 8;
            xr0 = xb[(size_t)ej * BB + e0];
            xr1 = xb[(size_t)ej * BB + e0 + 4];
            xz0 = xb[(size_t)(HH + ej) * BB + e0];
            xz1 = xb[(size_t)(HH + ej) * BB + e0 + 4];
            xn0 = xb[(size_t)(2 * HH + ej) * BB + e0];
            xn1 = xb[(size_t)(2 * HH + ej) * BB + e0 + 4];
        }

        // ---- FMA: 16 ds_read_b128, 384 v_fma per lane
        float acc[3][8] = {};
        #pragma unroll
        for (int q = 0; q < 4; ++q) {
            const int cb = q * 16 + s * 4;
            #pragma unroll
            for (int b = 0; b < 8; ++b) {
                f32x4 h4 = *(const f32x4*)&hs[wv][b * 64 + ((cb + 8 * b) & 63)];
                #pragma unroll
                for (int gate = 0; gate < 3; ++gate)
                    acc[gate][b] += ws4[gate][q].x * h4.x + ws4[gate][q].y * h4.y
                                  + ws4[gate][q].z * h4.z + ws4[gate][q].w * h4.w;
            }
        }
        // k-reduce across the 4 s-lanes of each quad (VALU DPP)
        #pragma unroll
        for (int gate = 0; gate < 3; ++gate)
            #pragma unroll
            for (int b = 0; b < 8; ++b)
                acc[gate][b] = quad_sum(acc[gate][b]);

        // s-lane s (<3) writes gate-s partials, rotated 8-slot rows (static idx)
        if (s < 3) {
            const int rot = (2 * ((g >> 2) + s)) & 7;
            #pragma unroll
            for (int hp = 0; hp < 4; ++hp) {
                const int b = hp * 2;
                float e0v = (s == 0) ? acc[0][b]     : (s == 1) ? acc[1][b]     : acc[2][b];
                float e1v = (s == 0) ? acc[0][b + 1] : (s == 1) ? acc[1][b + 1] : acc[2][b + 1];
                const int bp = (b + rot) & 7;
                *(float2*)&part[wv][s][g][bp] = make_float2(e0v, e1v);
            }
        }
        block_sync_lds();   // sync1: partials + hs ready; waves 1-7 head to sync2

        if (wv == 0) {
            // ---- epilogue: 16 units x 8 batches on one wave (2 outputs/lane)
            float hn0, hn1;
            #pragma unroll
            for (int pass = 0; pass < 2; ++pass) {
                const int eb = e0 + pass * 4;
                const int bp0 = (eb + 2 * (rb + 0)) & 7;
                const int bp1 = (eb + 2 * (rb + 1)) & 7;
                const int bp2 = (eb + 2 * (rb + 2)) & 7;
                float sg0 = 0.f, sg1 = 0.f, sg2 = 0.f;
                #pragma unroll
                for (int w = 0; w < 8; ++w) {
                    sg0 += part[w][0][eu][bp0];
                    sg1 += part[w][1][eu][bp1];
                    sg2 += part[w][2][eu][bp2];
                }
                float hprev = hs[slab][eb * 64 + ((kc + 8 * eb) & 63)];
                float xr = pass ? xr1 : xr0;
                float xz = pass ? xz1 : xz0;
                float xn = pass ? xn1 : xn0;
                float rg = 1.f / (1.f + expf(-(xr + sg0 + bhr)));
                float zg = 1.f / (1.f + expf(-(xz + sg1 + bhz)));
                float ng = tanhf(xn + rg * (sg2 + bhn));
                float hn = (1.f - zg) * ng + zg * hprev;
                llc_store1(hA + (size_t)((t + 1) & 1) * (HH * BB)
                              + (size_t)(bg * 8 + eb) * HH + ej, hn);
                if (pass == 0) hn0 = hn; else hn1 = hn;
            }
            // drain THIS WAVE's h stores, then signal (no block barrier needed)
            asm volatile("s_waitcnt vmcnt(0)" ::: "memory");
            if (lane == 0 && t + 1 < LL)
                __hip_atomic_store(&cells[bid * 4], (unsigned)(t + 1),
                                   __ATOMIC_RELAXED, __HIP_MEMORY_SCOPE_AGENT);
            // HBM result store AFTER the signal (ack overlaps the poll)
            gruT2[((size_t)t * BB + bg * 8 + e0) * HH + ej] = hn0;
            gruT2[((size_t)t * BB + bg * 8 + e0 + 4) * HH + ej] = hn1;
            // ---- poll gen t+1 from all 32 producers of this bg (with backoff)
            if (t + 1 < LL) {
                const unsigned want = (unsigned)(t + 1);
                for (;;) {
                    unsigned v = want;
                    if (lane < 32)
                        v = __hip_atomic_load(&cells[(bg * 32 + lane) * 4],
                                              __ATOMIC_RELAXED, __HIP_MEMORY_SCOPE_AGENT);
                    if (__all((int)(v >= want))) break;
                    __builtin_amdgcn_s_sleep(2);
                }
            }
        }
        block_sync_lds();   // sync2: gen t+1 ready; hs/part reusable
    }
}

// -------- mvals[b,t] = threshold( dot(h_t, M2[q-1]) + mb[q-1] ) --------
__global__ __launch_bounds__(256) void mval_kernel(
    const float* __restrict__ gruT2,   // [200][64][512]
    const float* __restrict__ M2,      // [1024][512]
    const float* __restrict__ mb,
    const int* __restrict__ qint,      // [B][L]
    float* __restrict__ mval)          // [B][L]
{
    int t = blockIdx.x;
    int wave = threadIdx.x >> 6, l = threadIdx.x & 63;
    for (int ii = 0; ii < 16; ++ii) {
        int b = wave * 16 + ii;
        int q = qint[b * LL + t] - 1;
        const float4* hp = (const float4*)(gruT2 + ((size_t)t * BB + b) * HH);
        const float4* mp = (const float4*)(M2 + (size_t)q * HH);
        float4 h0 = hp[l], m0 = mp[l];
        float4 h1 = hp[64 + l], m1 = mp[64 + l];
        float acc = h0.x * m0.x + h0.y * m0.y + h0.z * m0.z + h0.w * m0.w
                  + h1.x * m1.x + h1.y * m1.y + h1.z * m1.z + h1.w * m1.w;
        acc = wave_sum64(acc);
        if (l == 0) {
            float sv = acc + mb[q];
            mval[b * LL + t] = (sv >= 0.4f) ? 1.0f : sv;
        }
    }
}

// -------- per-(b,t) counting statistics --------
__global__ __launch_bounds__(256) void stats_kernel(
    const int* __restrict__ qint, const int* __restrict__ qaint,
    const float* __restrict__ mval,
    float* __restrict__ mc, float* __restrict__ mi,
    float* __restrict__ nmc, float* __restrict__ aa)
{
    int b = blockIdx.x, tid = threadIdx.x;
    __shared__ int qs[LL];
    __shared__ int qas[LL];
    __shared__ float mv[LL];
    if (tid < LL) {
        qs[tid] = qint[b * LL + tid];
        qas[tid] = qaint[b * LL + tid];
        mv[tid] = mval[b * LL + tid];
    }
    __syncthreads();
    int t = tid;
    if (t < LL) {
        int qt = qs[t];
        float smc = 0.f, smi = 0.f, snmc = 0.f, saa = 0.f;
        for (int k = 0; k <= t; ++k) {
            if (qs[k] == qt) {
                saa += 1.f;
                if (k < t) {
                    float mk = (mv[k] == 1.f) ? 1.f : 0.f;
                    float nk = (mv[k] == 0.f) ? 1.f : 0.f;
                    float a1 = (qas[k] == 1) ? 1.f : 0.f;
                    smc += a1 * mk;
                    smi += (1.f - a1) * mk;
                    snmc += (1.f - a1) * nk;
                }
            }
        }
        mc[b * LL + t] = smc;
        mi[b * LL + t] = smi;
        nmc[b * LL + t] = snmc;
        aa[b * LL + t] = saa;
    }
}

// -------- sequential DINA scan per batch --------
__global__ __launch_bounds__(256) void dina_kernel(
    const int* __restrict__ qint, const int* __restrict__ qaint,
    const float* __restrict__ mval,
    const float* __restrict__ mc, const float* __restrict__ mi,
    const float* __restrict__ nmc, const float* __restrict__ aa,
    float* __restrict__ preds)
{
    int b = blockIdx.x, tid = threadIdx.x;
    __shared__ float guess[QQ], slip[QQ];
    __shared__ float s_m[LL], s_mc[LL], s_mi[LL], s_nmc[LL], s_aa[LL];
    __shared__ int s_i[LL], s_qa[LL];
    for (int i = tid; i < QQ; i += 256) { guess[i] = 0.f; slip[i] = 0.f; }
    if (tid < LL) {
        s_m[tid] = mval[b * LL + tid];
        s_mc[tid] = mc[b * LL + tid];
        s_mi[tid] = mi[b * LL + tid];
        s_nmc[tid] = nmc[b * LL + tid];
        s_aa[tid] = aa[b * LL + tid];
        s_i[tid] = qint[b * LL + tid] - 1;
        s_qa[tid] = qaint[b * LL + tid];
    }
    __syncthreads();
    if (tid == 0) {
        for (int t = 0; t < LL; ++t) {
            int i = s_i[t];
            float m = s_m[t];
            int qa = s_qa[t];
            float aat = s_aa[t];
            float g_upd = (m == 1.f) ? s_mc[t] / aat
                          : ((qa == 0) ? 1.f - s_nmc[t] / aat : s_nmc[t] / aat);
            bool us = (m == 1.f) && (qa == 0);
            float ng = us ? guess[i] : g_upd;
            float ns = us ? s_mi[t] / aat : slip[i];
            guess[i] = ng;
            slip[i] = ns;
            preds[b * LL + t] = (1.f - ns) * (m * ng + (1.f - ns) * (1.f - m));
        }
    }
}

// -------- masked MSE + sigmoid outputs --------
__global__ __launch_bounds__(256) void loss_kernel(
    const float* __restrict__ preds, const float* __restrict__ target,
    float* __restrict__ out, float* __restrict__ acc)
{
    int r = blockIdx.x * 256 + threadIdx.x;
    float lm = 0.f, lc = 0.f;
    if (r < BL) {
        float p = preds[r], lab = target[r];
        float msk = (lab > -0.9f) ? 1.f : 0.f;
        float d = p - lab;
        lm = d * d * msk;
        lc = msk;
        out[1 + r] = 1.f / (1.f + expf(-p));
    }
    lm = wave_sum64(lm);
    lc = wave_sum64(lc);
    __shared__ float sm[4], sc[4];
    int lane = threadIdx.x & 63, w = threadIdx.x >> 6;
    if (lane == 0) { sm[w] = lm; sc[w] = lc; }
    __syncthreads();
    if (threadIdx.x == 0) {
        atomicAdd(&acc[1], sm[0] + sm[1] + sm[2] + sm[3]);
        atomicAdd(&acc[2], sc[0] + sc[1] + sc[2] + sc[3]);
    }
}

__global__ void final_kernel(const float* __restrict__ acc, float* __restrict__ out)
{
    out[0] = acc[1] + acc[0] * 1e-5f;
    out[1 + BL] = acc[2];
}

extern "C" void kernel_launch(void* const* d_in, const int* in_sizes, int n_in,
                              void* d_out, int out_size, void* d_ws, size_t ws_size,
                              hipStream_t stream) {
    const int* q_data = (const int*)d_in[0];
    const int* qa_data = (const int*)d_in[1];
    const int* pid_data = (const int*)d_in[2];
    const float* matrix = (const float*)d_in[3];
    const float* target = (const float*)d_in[4];
    const float* q_emb = (const float*)d_in[5];
    const float* qa_emb = (const float*)d_in[6];
    const float* q_emb_diff = (const float*)d_in[7];
    const float* qa_emb_diff = (const float*)d_in[8];
    const float* diff_parm = (const float*)d_in[9];
    const float* w_ih = (const float*)d_in[10];
    const float* w_hh = (const float*)d_in[11];
    const float* b_ih = (const float*)d_in[12];
    const float* b_hh = (const float*)d_in[13];
    const float* fc_w = (const float*)d_in[14];
    const float* fc_b = (const float*)d_in[15];
    float* out = (float*)d_out;
    float* W = (float*)d_ws;

    float* acc = W + OFF_ACC;
    unsigned int* cells = (unsigned int*)(W + OFF_CELLS);
    float* hA = W + OFF_HA;
    float* Aq = W + OFF_AQ;
    float* Dq = W + OFF_DQ;
    float* Bqa = W + OFF_BQA;
    float* Cqa = W + OFF_CQA;
    float* wsum = W + OFF_WSUM;
    float* fcwT = W + OFF_FCWT;
    float* M2 = W + OFF_M2;
    float* mb = W + OFF_MB;
    float* xgT = W + OFF_XG;
    float* m2parts = W + OFF_XG;       // temp: reused before xgT is written
    float* gruT2 = W + OFF_GRUT;
    int* qint = (int*)(W + OFF_QINT);
    int* qaint = (int*)(W + OFF_QAINT);
    float* pidf = W + OFF_PIDF;
    float* mval = W + OFF_MVAL;
    float* mc = W + OFF_MC;
    float* mi = W + OFF_MI;
    float* nmc = W + OFF_NMC;
    float* aa = W + OFF_AA;
    float* preds = W + OFF_PREDS;

    // zero accumulators + barrier cells + both h buffers (contiguous at ws start)
    hipMemsetAsync(W, 0, (OFF_HA + 2 * HH * BB) * sizeof(float), stream);

    prep_meta<<<50, 256, 0, stream>>>(q_data, qa_data, pid_data, diff_parm,
                                      qint, qaint, pidf, acc);
    wsum_kernel<<<G3, 256, 0, stream>>>(w_ih, wsum);
    transpose_kernel<<<dim3(16, 32), 256, 0, stream>>>(fc_w, fcwT, QQ, HH);

    // Bqa/Cqa batched
    gemm_nt_dual<<<dim3(24, 1, 2), 256, 0, stream>>>(
        qa_emb, qa_emb_diff, DD, w_ih, w_ih, 2 * DD, 2 * DD,
        Bqa, Cqa, G3, 2, G3, DD, b_ih, nullptr);
    // Aq/Dq batched
    gemm_nt_dual<<<dim3(24, 17, 2), 256, 0, stream>>>(
        q_emb, q_emb_diff, DD, wsum, w_ih + DD, DD, 2 * DD,
        Aq, Dq, G3, NQ + 1, G3, DD, nullptr, nullptr);
    // M2 = matrix . fc_w  (split-K x4 into temp region, then reduce)
    gemm_nt_splitk<<<dim3(8, 16, 4), 256, 0, stream>>>(
        matrix, QQ, fcwT, QQ, m2parts, HH, QQ, HH, QQ / 4);
    reduce4_kernel<<<2048, 256, 0, stream>>>(m2parts, M2, QQ * HH);
    mb_kernel<<<QQ, 256, 0, stream>>>(matrix, fc_b, mb);

    // xgT gather+transpose (overwrites the m2parts temp region)
    xgt_kernel<<<LL, 512, 0, stream>>>(Aq, Bqa, Cqa, Dq, qint, qaint, pidf, xgT);

    gru_persist<<<GBLK, 512, 0, stream>>>(xgT, w_hh, b_hh, hA, gruT2, cells);

    mval_kernel<<<LL, 256, 0, stream>>>(gruT2, M2, mb, qint, mval);
    stats_kernel<<<BB, 256, 0, stream>>>(qint, qaint, mval, mc, mi, nmc, aa);
    dina_kernel<<<BB, 256, 0, stream>>>(qint, qaint, mval, mc, mi, nmc, aa, preds);
    loss_kernel<<<50, 256, 0, stream>>>(preds, target, out, acc);
    final_kernel<<<1, 1, 0, stream>>>(acc, out);
}

// Round 5
// 1184.052 us; speedup vs baseline: 2.0178x; 1.1799x over previous
//
#include <hip/hip_runtime.h>
#include <hip/hip_bf16.h>
#include <math.h>

// Problem constants
#define BB 64
#define LL 200
#define NQ 1024
#define DD 256
#define HH 512
#define QQ 1024
#define G3 1536   // 3*H
#define BL 12800  // B*L
#define GBLK 256  // persistent GRU blocks (1/CU); +130 overlap workers
#define NWRK 130  // 128 M2-GEMM workers + 2 mb workers

// ---------------- workspace layout (in floats) ----------------
#define OFF_ACC   ((size_t)0)                    // [0]=creg_raw [1]=mse [2]=maskcnt
#define OFF_CELLS ((size_t)16)                   // 256 cells, 16B apart (1024 uints)
#define OFF_HA    ((size_t)1056)                 // hA[2][64][512] batch-major
#define OFF_AQ    (OFF_HA + 65536)               // 1025*1536
#define OFF_DQ    (OFF_AQ + 1574400)
#define OFF_BQA   (OFF_DQ + 1574400)             // 2*1536
#define OFF_CQA   (OFF_BQA + 3072)
#define OFF_WSUM  (OFF_CQA + 3072)               // 1536*256
#define OFF_FCWT  (OFF_WSUM + 393216)            // (unused now)
#define OFF_M2    (OFF_FCWT + 524288)            // 1024*512
#define OFF_MB    (OFF_M2 + 524288)              // 1024
#define OFF_XG    (OFF_MB + 1024)                // xgT [t][g][b]
#define OFF_GRUT  (OFF_XG + 19660800)            // [t][b][k]
#define OFF_QINT  (OFF_GRUT + 6553600)           // 12800 ints [B][L]
#define OFF_QAINT (OFF_QINT + 12800)
#define OFF_PIDF  (OFF_QAINT + 12800)
#define OFF_MVAL  (OFF_PIDF + 12800)
#define OFF_MC    (OFF_MVAL + 12800)
#define OFF_MI    (OFF_MC + 12800)
#define OFF_NMC   (OFF_MI + 12800)
#define OFF_AA    (OFF_NMC + 12800)
#define OFF_PREDS (OFF_AA + 12800)

typedef float f32x4 __attribute__((ext_vector_type(4)));

__device__ __forceinline__ float wave_sum64(float v) {
    #pragma unroll
    for (int o = 32; o > 0; o >>= 1) v += __shfl_down(v, o, 64);
    return v;
}

// LLC-coherent (bypass L1/L2) ops
__device__ __forceinline__ f32x4 llc_load4(const float* p) {
    f32x4 v;
    asm volatile("global_load_dwordx4 %0, %1, off sc0 sc1" : "=v"(v) : "v"(p));
    return v;
}
__device__ __forceinline__ void llc_wait2(f32x4& a, f32x4& b) {
    asm volatile("s_waitcnt vmcnt(0)" : "+v"(a), "+v"(b));
}
__device__ __forceinline__ void llc_store1(float* p, float v) {
    asm volatile("global_store_dword %0, %1, off sc0 sc1" :: "v"(p), "v"(v) : "memory");
}

// quad (4-lane) butterfly sum via DPP quad_perm (VALU pipe, not LDS)
__device__ __forceinline__ float quad_sum(float v) {
    float t1 = __int_as_float(__builtin_amdgcn_update_dpp(
        0, __float_as_int(v), 0xB1, 0xF, 0xF, true));   // quad_perm xor1
    v += t1;
    float t2 = __int_as_float(__builtin_amdgcn_update_dpp(
        0, __float_as_int(v), 0x4E, 0xF, 0xF, true));   // quad_perm xor2
    return v + t2;
}

// -------- meta: q, qa, pid per (b,t); c_reg accumulation --------
__global__ __launch_bounds__(256) void prep_meta(
    const int* __restrict__ q_data, const int* __restrict__ qa_data,
    const int* __restrict__ pid_data, const float* __restrict__ diff_parm,
    int* __restrict__ qint, int* __restrict__ qaint, float* __restrict__ pidf,
    float* __restrict__ acc)
{
    int r = blockIdx.x * 256 + threadIdx.x;
    float pp = 0.f;
    if (r < BL) {
        int q = q_data[r];
        qint[r] = q;
        qaint[r] = (qa_data[r] - q) / NQ;
        float pid = diff_parm[pid_data[r]];
        pidf[r] = pid;
        pp = pid * pid;
    }
    pp = wave_sum64(pp);
    __shared__ float sm[4];
    int lane = threadIdx.x & 63, w = threadIdx.x >> 6;
    if (lane == 0) sm[w] = pp;
    __syncthreads();
    if (threadIdx.x == 0) atomicAdd(&acc[0], sm[0] + sm[1] + sm[2] + sm[3]);
}

// -------- wsum[g,d] = w_ih[g,d] + w_ih[g,256+d] --------
__global__ __launch_bounds__(256) void wsum_kernel(const float* __restrict__ w_ih,
                                                   float* __restrict__ wsum)
{
    int g = blockIdx.x, d = threadIdx.x;
    wsum[(size_t)g * DD + d] = w_ih[(size_t)g * 2 * DD + d] + w_ih[(size_t)g * 2 * DD + DD + d];
}

// -------- dual-batched NT GEMM (two independent problems, z picks) --------
__global__ __launch_bounds__(256) void gemm_nt_dual(
    const float* __restrict__ A0, const float* __restrict__ A1, int lda,
    const float* __restrict__ B0, const float* __restrict__ B1, int ldb0, int ldb1,
    float* __restrict__ C0, float* __restrict__ C1, int ldc,
    int M, int N, int K,
    const float* __restrict__ bias0, const float* __restrict__ bias1)
{
    const int z = blockIdx.z;
    const float* A = z ? A1 : A0;
    const float* B = z ? B1 : B0;
    float* C = z ? C1 : C0;
    const int ldb = z ? ldb1 : ldb0;
    const float* bias = z ? bias1 : bias0;

    __shared__ float As[16][65];
    __shared__ float Bs[16][65];
    const int bm = blockIdx.y * 64, bn = blockIdx.x * 64;
    const int tid = threadIdx.x;
    const int tx = tid & 15, ty = tid >> 4;
    const int mm = tid >> 4, kk = tid & 15;
    float acc[4][4] = {};
    float ar[4], br[4];
    #pragma unroll
    for (int i = 0; i < 4; ++i) {
        int m = bm + mm + 16 * i;
        ar[i] = (m < M) ? A[(size_t)m * lda + kk] : 0.f;
        int n = bn + mm + 16 * i;
        br[i] = (n < N) ? B[(size_t)n * ldb + kk] : 0.f;
    }
    for (int k0 = 0; k0 < K; k0 += 16) {
        #pragma unroll
        for (int i = 0; i < 4; ++i) { As[kk][mm + 16 * i] = ar[i]; Bs[kk][mm + 16 * i] = br[i]; }
        __syncthreads();
        int kn = k0 + 16;
        if (kn < K) {
            #pragma unroll
            for (int i = 0; i < 4; ++i) {
                int m = bm + mm + 16 * i;
                ar[i] = (m < M) ? A[(size_t)m * lda + kn + kk] : 0.f;
                int n = bn + mm + 16 * i;
                br[i] = (n < N) ? B[(size_t)n * ldb + kn + kk] : 0.f;
            }
        }
        #pragma unroll
        for (int kq = 0; kq < 16; ++kq) {
            float a[4], b[4];
            #pragma unroll
            for (int i = 0; i < 4; ++i) a[i] = As[kq][ty * 4 + i];
            #pragma unroll
            for (int j = 0; j < 4; ++j) b[j] = Bs[kq][tx * 4 + j];
            #pragma unroll
            for (int i = 0; i < 4; ++i)
                #pragma unroll
                for (int j = 0; j < 4; ++j) acc[i][j] += a[i] * b[j];
        }
        __syncthreads();
    }
    #pragma unroll
    for (int i = 0; i < 4; ++i) {
        int m = bm + ty * 4 + i;
        if (m >= M) continue;
        #pragma unroll
        for (int j = 0; j < 4; ++j) {
            int n = bn + tx * 4 + j;
            if (n >= N) continue;
            C[(size_t)m * ldc + n] = acc[i][j] + (bias ? bias[n] : 0.f);
        }
    }
}

// -------- fused xg gather + transpose: xgT[t][g][b] --------
__global__ __launch_bounds__(512) void xgt_kernel(
    const float* __restrict__ Aq, const float* __restrict__ Bqa,
    const float* __restrict__ Cqa, const float* __restrict__ Dq,
    const int* __restrict__ qint, const int* __restrict__ qaint,
    const float* __restrict__ pidf, float* __restrict__ xgT)
{
    const int t = blockIdx.x;
    __shared__ float tile[64][129];
    __shared__ int qs[BB];
    __shared__ int qas[BB];
    __shared__ float ps[BB];
    const int tid = threadIdx.x;
    if (tid < BB) {
        qs[tid] = qint[tid * LL + t];
        qas[tid] = qaint[tid * LL + t];
        ps[tid] = pidf[tid * LL + t];
    }
    __syncthreads();
    for (int g0 = 0; g0 < G3; g0 += 128) {
        #pragma unroll
        for (int it = 0; it < 16; ++it) {
            int idx = it * 512 + tid;
            int b = idx >> 7, gg = idx & 127;
            int g = g0 + gg;
            int q = qs[b], qa = qas[b];
            float pid = ps[b];
            tile[b][gg] = Aq[(size_t)q * G3 + g] + Bqa[(size_t)qa * G3 + g]
                        + pid * (Cqa[(size_t)qa * G3 + g] + Dq[(size_t)q * G3 + g]);
        }
        __syncthreads();
        #pragma unroll
        for (int it = 0; it < 16; ++it) {
            int idx = it * 512 + tid;
            int gg = idx >> 6, b = idx & 63;
            xgT[((size_t)t * G3 + g0 + gg) * BB + b] = tile[b][gg];
        }
        __syncthreads();
    }
}

// ================== persistent GRU (R1-852 verbatim) + overlap workers ==================
// Blocks 0..255: the measured-best 852us GRU schedule, UNCHANGED (8 bg x 32 ug;
// 8 batches x 16 units/block; weights in regs; per-wave LLC h staging; 3 barriers;
// tid<128 epilogue; wave-0 poll with s_sleep(2) backoff; signal after drain+barrier).
// Blocks 256..383: M2 = matrix . fc_w (NN GEMM, 64x64 tile, K=1024) — consumed only
// by mval (post-GRU), so it runs entirely in the GRU's stall shadow. Blocks 384..385:
// mb = matrix . fc_b. Workers are dependency-free: if co-residency fails they simply
// run after the GRU blocks (no deadlock). gru waves take s_setprio(1) so the
// latency-critical chain wins SIMD arbitration over bulk GEMM waves.
__global__ __launch_bounds__(512) void gru_persist(
    const float* __restrict__ xgT,     // [200][1536][64]
    const float* __restrict__ w_hh,    // [1536][512]
    const float* __restrict__ b_hh,    // [1536]
    float* __restrict__ hA,            // [2][64][512]  (batch-major)
    float* __restrict__ gruT2,         // [200][64][512]
    unsigned int* __restrict__ cells,  // 256 cells, 16B apart
    const float* __restrict__ matrix,  // [1024][1024]
    const float* __restrict__ fc_w,    // [1024][512]
    const float* __restrict__ fc_b,    // [1024]
    float* __restrict__ M2,            // [1024][512]
    float* __restrict__ mb)            // [1024]
{
    __shared__ float hs[8][512];          // per-wave staged h slice: [wave][b*64 + swz(col)]
    __shared__ float part[8][3][16][8];   // wave partials [wave][gate][unit][b(rotated)]
    __shared__ float As[16][65];          // worker GEMM tiles (worker blocks only)
    __shared__ float Bs[16][65];

    const int tid = threadIdx.x;
    const int bid = blockIdx.x;

    if (bid >= GBLK) {
        // ================= overlap workers =================
        const int widx = bid - GBLK;
        if (widx >= 128) {
            // mb[k] = sum_q matrix[k][q]*fc_b[q]; 2 blocks x 8 waves x 64 rows
            const int wv2 = tid >> 6, lane2 = tid & 63;
            const int kb = (widx - 128) * 512 + wv2 * 64;
            for (int i = 0; i < 64; ++i) {
                const float* mrow = matrix + (size_t)(kb + i) * QQ;
                float sacc = 0.f;
                #pragma unroll
                for (int j = 0; j < 16; ++j)
                    sacc += mrow[lane2 + 64 * j] * fc_b[lane2 + 64 * j];
                sacc = wave_sum64(sacc);
                if (lane2 == 0) mb[kb + i] = sacc;
            }
            return;
        }
        // M2 NN GEMM: C[1024][512] = matrix[1024][1024] . fc_w[1024][512]
        const int bm = (widx >> 3) * 64, bn = (widx & 7) * 64;
        const int mm = tid >> 4, kk = tid & 15;   // A stage (rows mm, mm+32)
        const int nn = tid & 31, k2 = tid >> 5;   // B stage (k rows k2)
        const int tx = tid & 15, ty = tid >> 4;   // compute: 32x16 threads, 2x4 acc
        float acc[2][4] = {};
        for (int k0 = 0; k0 < QQ; k0 += 16) {
            if (k0) __syncthreads();
            As[kk][mm]      = matrix[(size_t)(bm + mm) * QQ + k0 + kk];
            As[kk][mm + 32] = matrix[(size_t)(bm + mm + 32) * QQ + k0 + kk];
            Bs[k2][nn]      = fc_w[(size_t)(k0 + k2) * HH + bn + nn];
            Bs[k2][nn + 32] = fc_w[(size_t)(k0 + k2) * HH + bn + nn + 32];
            __syncthreads();
            #pragma unroll
            for (int kq = 0; kq < 16; ++kq) {
                float a0 = As[kq][ty * 2], a1 = As[kq][ty * 2 + 1];
                #pragma unroll
                for (int j = 0; j < 4; ++j) {
                    float bv = Bs[kq][tx * 4 + j];
                    acc[0][j] += a0 * bv;
                    acc[1][j] += a1 * bv;
                }
            }
        }
        #pragma unroll
        for (int i = 0; i < 2; ++i)
            #pragma unroll
            for (int j = 0; j < 4; ++j)
                M2[(size_t)(bm + ty * 2 + i) * HH + bn + tx * 4 + j] = acc[i][j];
        return;
    }

    // ================= GRU path (verbatim R1-852) =================
    __builtin_amdgcn_s_setprio(1);

    const int bg = bid >> 5;              // batch group 0..7 (8 batches)
    const int j0 = (bid & 31) * 16;       // first unit of this block
    const int wv = tid >> 6;              // 0..7 k-slice (64 k each)
    const int lane = tid & 63;
    const int g = lane >> 2;              // unit offset 0..15
    const int s = lane & 3;               // k sub-slice 0..3

    // ---- w_hh fragment in registers: 3 gates x 4 q x f32x4 = 48 floats/lane
    f32x4 ws4[3][4];
    #pragma unroll
    for (int gate = 0; gate < 3; ++gate)
        #pragma unroll
        for (int q = 0; q < 4; ++q)
            ws4[gate][q] = *(const f32x4*)&w_hh[
                (size_t)(gate * HH + j0 + g) * HH + wv * 64 + q * 16 + s * 4];

    // epilogue mapping (tid<128): unit eu, batch eb
    const int eu = tid >> 3;              // 0..15 when tid<128
    const int eb = tid & 7;
    float bhr = 0.f, bhz = 0.f, bhn = 0.f;
    if (tid < 128) {
        bhr = b_hh[j0 + eu];
        bhz = b_hh[HH + j0 + eu];
        bhn = b_hh[2 * HH + j0 + eu];
    }

    // staging split: lane's two 16B chunks of the wave's [8 b][64 k] slice
    const int b0 = lane >> 4;             // rows b0 and b0+4
    const int c0 = (lane & 15) * 4;       // col within k-slice

    for (int t = 0; t < LL; ++t) {
        // xg prefetch (read-only, cached) - hides HBM latency under the poll
        float xr = 0.f, xz = 0.f, xn = 0.f;
        if (tid < 128) {
            const float* xb = xgT + (size_t)t * G3 * BB;
            int col = bg * 8 + eb;
            xr = xb[(size_t)(j0 + eu) * BB + col];
            xz = xb[(size_t)(HH + j0 + eu) * BB + col];
            xn = xb[(size_t)(2 * HH + j0 + eu) * BB + col];
        }
        // wave 0: wait until all 32 blocks of this batch-group finished step t-1
        if (t && tid < 64) {
            const unsigned want = (unsigned)t;
            for (;;) {
                unsigned v = want;
                if (lane < 32)
                    v = __hip_atomic_load(&cells[(bg * 32 + lane) * 4],
                                          __ATOMIC_RELAXED, __HIP_MEMORY_SCOPE_AGENT);
                if (__all((int)(v >= want))) break;
                __builtin_amdgcn_s_sleep(2);
            }
        }
        __syncthreads();

        // ---- stage h[t&1] slice (coherent LLC loads, dense 1KB/wave/inst)
        {
            const float* hcur = hA + (size_t)(t & 1) * (HH * BB);
            const float* p0 = hcur + (size_t)(bg * 8 + b0) * HH + wv * 64 + c0;
            f32x4 va = llc_load4(p0);
            f32x4 vb = llc_load4(p0 + 4 * HH);
            llc_wait2(va, vb);
            *(f32x4*)&hs[wv][b0 * 64 + ((c0 + 8 * b0) & 63)] = va;
            *(f32x4*)&hs[wv][(b0 + 4) * 64 + ((c0 + 8 * b0 + 32) & 63)] = vb;
        }

        // ---- FMA: per-lane ds_read_b128 + 384 v_fma
        float acc[3][8];
        #pragma unroll
        for (int gate = 0; gate < 3; ++gate) {
            #pragma unroll
            for (int b = 0; b < 8; ++b) acc[gate][b] = 0.f;
        }
        #pragma unroll
        for (int q = 0; q < 4; ++q) {
            const int cb = q * 16 + s * 4;
            #pragma unroll
            for (int b = 0; b < 8; ++b) {
                f32x4 h4 = *(const f32x4*)&hs[wv][b * 64 + ((cb + 8 * b) & 63)];
                #pragma unroll
                for (int gate = 0; gate < 3; ++gate) {
                    acc[gate][b] += ws4[gate][q].x * h4.x + ws4[gate][q].y * h4.y
                                  + ws4[gate][q].z * h4.z + ws4[gate][q].w * h4.w;
                }
            }
        }

        // k-reduce across the 4 s-lanes of each quad (VALU DPP)
        #pragma unroll
        for (int gate = 0; gate < 3; ++gate)
            #pragma unroll
            for (int b = 0; b < 8; ++b)
                acc[gate][b] = quad_sum(acc[gate][b]);

        // s-lane s (<3) writes gate s partials, columns rotated to spread banks.
        if (s < 3) {
            const int rot = (2 * ((g >> 2) + s)) & 7;
            #pragma unroll
            for (int hp = 0; hp < 4; ++hp) {
                const int b = hp * 2;
                float e0 = (s == 0) ? acc[0][b]     : (s == 1) ? acc[1][b]     : acc[2][b];
                float e1 = (s == 0) ? acc[0][b + 1] : (s == 1) ? acc[1][b + 1] : acc[2][b + 1];
                const int bp = (b + rot) & 7;
                *(float2*)&part[wv][s][g][bp] = make_float2(e0, e1);
            }
        }
        __syncthreads();

        // ---- 8-wave reduce + gates + h store (tid<128: 16 units x 8 batches)
        if (tid < 128) {
            const int rb = eu >> 2;
            const int bp0 = (eb + 2 * (rb + 0)) & 7;
            const int bp1 = (eb + 2 * (rb + 1)) & 7;
            const int bp2 = (eb + 2 * (rb + 2)) & 7;
            float sg0 = 0.f, sg1 = 0.f, sg2 = 0.f;
            #pragma unroll
            for (int w = 0; w < 8; ++w) {
                sg0 += part[w][0][eu][bp0];
                sg1 += part[w][1][eu][bp1];
                sg2 += part[w][2][eu][bp2];
            }
            const int ku = j0 + eu;
            float hprev = hs[ku >> 6][eb * 64 + (((ku & 63) + 8 * eb) & 63)];
            float rg = 1.f / (1.f + expf(-(xr + sg0 + bhr)));
            float zg = 1.f / (1.f + expf(-(xz + sg1 + bhz)));
            float ng = tanhf(xn + rg * (sg2 + bhn));
            float hn = (1.f - zg) * ng + zg * hprev;
            llc_store1(hA + (size_t)((t + 1) & 1) * (HH * BB)
                          + (size_t)(bg * 8 + eb) * HH + ku, hn);
            gruT2[((size_t)t * BB + bg * 8 + eb) * HH + ku] = hn;
            asm volatile("s_waitcnt vmcnt(0)" ::: "memory");
        }
        __syncthreads();
        if (tid == 0 && t + 1 < LL)
            __hip_atomic_store(&cells[bid * 4], (unsigned)(t + 1),
                               __ATOMIC_RELAXED, __HIP_MEMORY_SCOPE_AGENT);
    }
}

// -------- mvals[b,t] = threshold( dot(h_t, M2[q-1]) + mb[q-1] ) --------
__global__ __launch_bounds__(256) void mval_kernel(
    const float* __restrict__ gruT2,   // [200][64][512]
    const float* __restrict__ M2,      // [1024][512]
    const float* __restrict__ mb,
    const int* __restrict__ qint,      // [B][L]
    float* __restrict__ mval)          // [B][L]
{
    int t = blockIdx.x;
    int wave = threadIdx.x >> 6, l = threadIdx.x & 63;
    for (int ii = 0; ii < 16; ++ii) {
        int b = wave * 16 + ii;
        int q = qint[b * LL + t] - 1;
        const float4* hp = (const float4*)(gruT2 + ((size_t)t * BB + b) * HH);
        const float4* mp = (const float4*)(M2 + (size_t)q * HH);
        float4 h0 = hp[l], m0 = mp[l];
        float4 h1 = hp[64 + l], m1 = mp[64 + l];
        float acc = h0.x * m0.x + h0.y * m0.y + h0.z * m0.z + h0.w * m0.w
                  + h1.x * m1.x + h1.y * m1.y + h1.z * m1.z + h1.w * m1.w;
        acc = wave_sum64(acc);
        if (l == 0) {
            float sv = acc + mb[q];
            mval[b * LL + t] = (sv >= 0.4f) ? 1.0f : sv;
        }
    }
}

// -------- per-(b,t) counting statistics --------
__global__ __launch_bounds__(256) void stats_kernel(
    const int* __restrict__ qint, const int* __restrict__ qaint,
    const float* __restrict__ mval,
    float* __restrict__ mc, float* __restrict__ mi,
    float* __restrict__ nmc, float* __restrict__ aa)
{
    int b = blockIdx.x, tid = threadIdx.x;
    __shared__ int qs[LL];
    __shared__ int qas[LL];
    __shared__ float mv[LL];
    if (tid < LL) {
        qs[tid] = qint[b * LL + tid];
        qas[tid] = qaint[b * LL + tid];
        mv[tid] = mval[b * LL + tid];
    }
    __syncthreads();
    int t = tid;
    if (t < LL) {
        int qt = qs[t];
        float smc = 0.f, smi = 0.f, snmc = 0.f, saa = 0.f;
        for (int k = 0; k <= t; ++k) {
            if (qs[k] == qt) {
                saa += 1.f;
                if (k < t) {
                    float mk = (mv[k] == 1.f) ? 1.f : 0.f;
                    float nk = (mv[k] == 0.f) ? 1.f : 0.f;
                    float a1 = (qas[k] == 1) ? 1.f : 0.f;
                    smc += a1 * mk;
                    smi += (1.f - a1) * mk;
                    snmc += (1.f - a1) * nk;
                }
            }
        }
        mc[b * LL + t] = smc;
        mi[b * LL + t] = smi;
        nmc[b * LL + t] = snmc;
        aa[b * LL + t] = saa;
    }
}

// -------- sequential DINA scan per batch --------
__global__ __launch_bounds__(256) void dina_kernel(
    const int* __restrict__ qint, const int* __restrict__ qaint,
    const float* __restrict__ mval,
    const float* __restrict__ mc, const float* __restrict__ mi,
    const float* __restrict__ nmc, const float* __restrict__ aa,
    float* __restrict__ preds)
{
    int b = blockIdx.x, tid = threadIdx.x;
    __shared__ float guess[QQ], slip[QQ];
    __shared__ float s_m[LL], s_mc[LL], s_mi[LL], s_nmc[LL], s_aa[LL];
    __shared__ int s_i[LL], s_qa[LL];
    for (int i = tid; i < QQ; i += 256) { guess[i] = 0.f; slip[i] = 0.f; }
    if (tid < LL) {
        s_m[tid] = mval[b * LL + tid];
        s_mc[tid] = mc[b * LL + tid];
        s_mi[tid] = mi[b * LL + tid];
        s_nmc[tid] = nmc[b * LL + tid];
        s_aa[tid] = aa[b * LL + tid];
        s_i[tid] = qint[b * LL + tid] - 1;
        s_qa[tid] = qaint[b * LL + tid];
    }
    __syncthreads();
    if (tid == 0) {
        for (int t = 0; t < LL; ++t) {
            int i = s_i[t];
            float m = s_m[t];
            int qa = s_qa[t];
            float aat = s_aa[t];
            float g_upd = (m == 1.f) ? s_mc[t] / aat
                          : ((qa == 0) ? 1.f - s_nmc[t] / aat : s_nmc[t] / aat);
            bool us = (m == 1.f) && (qa == 0);
            float ng = us ? guess[i] : g_upd;
            float ns = us ? s_mi[t] / aat : slip[i];
            guess[i] = ng;
            slip[i] = ns;
            preds[b * LL + t] = (1.f - ns) * (m * ng + (1.f - ns) * (1.f - m));
        }
    }
}

// -------- masked MSE + sigmoid outputs --------
__global__ __launch_bounds__(256) void loss_kernel(
    const float* __restrict__ preds, const float* __restrict__ target,
    float* __restrict__ out, float* __restrict__ acc)
{
    int r = blockIdx.x * 256 + threadIdx.x;
    float lm = 0.f, lc = 0.f;
    if (r < BL) {
        float p = preds[r], lab = target[r];
        float msk = (lab > -0.9f) ? 1.f : 0.f;
        float d = p - lab;
        lm = d * d * msk;
        lc = msk;
        out[1 + r] = 1.f / (1.f + expf(-p));
    }
    lm = wave_sum64(lm);
    lc = wave_sum64(lc);
    __shared__ float sm[4], sc[4];
    int lane = threadIdx.x & 63, w = threadIdx.x >> 6;
    if (lane == 0) { sm[w] = lm; sc[w] = lc; }
    __syncthreads();
    if (threadIdx.x == 0) {
        atomicAdd(&acc[1], sm[0] + sm[1] + sm[2] + sm[3]);
        atomicAdd(&acc[2], sc[0] + sc[1] + sc[2] + sc[3]);
    }
}

__global__ void final_kernel(const float* __restrict__ acc, float* __restrict__ out)
{
    out[0] = acc[1] + acc[0] * 1e-5f;
    out[1 + BL] = acc[2];
}

extern "C" void kernel_launch(void* const* d_in, const int* in_sizes, int n_in,
                              void* d_out, int out_size, void* d_ws, size_t ws_size,
                              hipStream_t stream) {
    const int* q_data = (const int*)d_in[0];
    const int* qa_data = (const int*)d_in[1];
    const int* pid_data = (const int*)d_in[2];
    const float* matrix = (const float*)d_in[3];
    const float* target = (const float*)d_in[4];
    const float* q_emb = (const float*)d_in[5];
    const float* qa_emb = (const float*)d_in[6];
    const float* q_emb_diff = (const float*)d_in[7];
    const float* qa_emb_diff = (const float*)d_in[8];
    const float* diff_parm = (const float*)d_in[9];
    const float* w_ih = (const float*)d_in[10];
    const float* w_hh = (const float*)d_in[11];
    const float* b_ih = (const float*)d_in[12];
    const float* b_hh = (const float*)d_in[13];
    const float* fc_w = (const float*)d_in[14];
    const float* fc_b = (const float*)d_in[15];
    float* out = (float*)d_out;
    float* W = (float*)d_ws;

    float* acc = W + OFF_ACC;
    unsigned int* cells = (unsigned int*)(W + OFF_CELLS);
    float* hA = W + OFF_HA;
    float* Aq = W + OFF_AQ;
    float* Dq = W + OFF_DQ;
    float* Bqa = W + OFF_BQA;
    float* Cqa = W + OFF_CQA;
    float* wsum = W + OFF_WSUM;
    float* M2 = W + OFF_M2;
    float* mb = W + OFF_MB;
    float* xgT = W + OFF_XG;
    float* gruT2 = W + OFF_GRUT;
    int* qint = (int*)(W + OFF_QINT);
    int* qaint = (int*)(W + OFF_QAINT);
    float* pidf = W + OFF_PIDF;
    float* mval = W + OFF_MVAL;
    float* mc = W + OFF_MC;
    float* mi = W + OFF_MI;
    float* nmc = W + OFF_NMC;
    float* aa = W + OFF_AA;
    float* preds = W + OFF_PREDS;

    // zero accumulators + barrier cells + both h buffers (contiguous at ws start)
    hipMemsetAsync(W, 0, (OFF_HA + 2 * HH * BB) * sizeof(float), stream);

    prep_meta<<<50, 256, 0, stream>>>(q_data, qa_data, pid_data, diff_parm,
                                      qint, qaint, pidf, acc);
    wsum_kernel<<<G3, 256, 0, stream>>>(w_ih, wsum);

    // Bqa/Cqa batched
    gemm_nt_dual<<<dim3(24, 1, 2), 256, 0, stream>>>(
        qa_emb, qa_emb_diff, DD, w_ih, w_ih, 2 * DD, 2 * DD,
        Bqa, Cqa, G3, 2, G3, DD, b_ih, nullptr);
    // Aq/Dq batched
    gemm_nt_dual<<<dim3(24, 17, 2), 256, 0, stream>>>(
        q_emb, q_emb_diff, DD, wsum, w_ih + DD, DD, 2 * DD,
        Aq, Dq, G3, NQ + 1, G3, DD, nullptr, nullptr);

    // xgT gather+transpose
    xgt_kernel<<<LL, 512, 0, stream>>>(Aq, Bqa, Cqa, Dq, qint, qaint, pidf, xgT);

    // fused: GRU (blocks 0..255) + M2/mb overlap workers (blocks 256..385)
    gru_persist<<<GBLK + NWRK, 512, 0, stream>>>(xgT, w_hh, b_hh, hA, gruT2, cells,
                                                 matrix, fc_w, fc_b, M2, mb);

    mval_kernel<<<LL, 256, 0, stream>>>(gruT2, M2, mb, qint, mval);
    stats_kernel<<<BB, 256, 0, stream>>>(qint, qaint, mval, mc, mi, nmc, aa);
    dina_kernel<<<BB, 256, 0, stream>>>(qint, qaint, mval, mc, mi, nmc, aa, preds);
    loss_kernel<<<50, 256, 0, stream>>>(preds, target, out, acc);
    final_kernel<<<1, 1, 0, stream>>>(acc, out);
}